// Round 1
// baseline (207.649 us; speedup 1.0000x reference)
//
#include <hip/hip_runtime.h>

typedef unsigned short u16;
typedef __attribute__((ext_vector_type(8))) __bf16 bf16x8;
typedef __attribute__((ext_vector_type(4))) float f32x4;
typedef __attribute__((ext_vector_type(4))) u16 u16x4;

// ---------------- helpers ----------------

__device__ __forceinline__ u16 f2bf(float f) {
  unsigned u = __float_as_uint(f);
  u += 0x7fff + ((u >> 16) & 1);   // RNE
  return (u16)(u >> 16);
}

__device__ __forceinline__ f32x4 mfma16(bf16x8 a, bf16x8 b, f32x4 c) {
  return __builtin_amdgcn_mfma_f32_16x16x32_bf16(a, b, c, 0, 0, 0);
}

__device__ __forceinline__ void gload16(const void* g, void* l) {
  __builtin_amdgcn_global_load_lds(
      (__attribute__((address_space(1))) unsigned int*)(const_cast<void*>(g)),
      (__attribute__((address_space(3))) unsigned int*)l, 16, 0, 0);
}

// ---------------- small prep kernels ----------------

__global__ void k_f32_to_bf16(const float* __restrict__ in, u16* __restrict__ out, int n4) {
  int i = blockIdx.x * blockDim.x + threadIdx.x;
  if (i < n4) {
    float4 v = reinterpret_cast<const float4*>(in)[i];
    u16x4 o;
    o.x = f2bf(v.x); o.y = f2bf(v.y); o.z = f2bf(v.z); o.w = f2bf(v.w);
    reinterpret_cast<u16x4*>(out)[i] = o;
  }
}

// Wt[n][k] = W[k][n], fp32 -> bf16. 32x32 tiles.
__global__ void k_transpose_w(const float* __restrict__ in, u16* __restrict__ out) {
  __shared__ float tile[32][33];
  const int r0 = blockIdx.y * 32, c0 = blockIdx.x * 32;
  const int t = threadIdx.x;
  for (int i = t; i < 1024; i += 256) {
    int r = i >> 5, c = i & 31;
    tile[r][c] = in[(size_t)(r0 + r) * 1024 + c0 + c];
  }
  __syncthreads();
  for (int i = t; i < 1024; i += 256) {
    int r = i >> 5, c = i & 31;
    out[(size_t)(c0 + r) * 1024 + r0 + c] = f2bf(tile[c][r]);
  }
}

__global__ void k_pack_bias(const float* __restrict__ bq, const float* __restrict__ bk,
                            const float* __restrict__ bv, float* __restrict__ out) {
  int i = blockIdx.x * 256 + threadIdx.x;
  if (i < 3072) out[i] = (i < 1024) ? bq[i] : (i < 2048 ? bk[i - 1024] : bv[i - 2048]);
}

// Vt[(b*16+h)*64 + d][s] = QKV[(b*1024+s)*3072 + 2048 + h*64 + d]
__global__ void k_transpose_v(const u16* __restrict__ qkv, u16* __restrict__ vt) {
  __shared__ u16 tile[64][65];
  const int bh = blockIdx.x >> 4;     // b*16+h
  const int st = blockIdx.x & 15;
  const int b = bh >> 4, h = bh & 15;
  const int s0 = st * 64;
  const int t = threadIdx.x;
  for (int i = t; i < 4096; i += 256) {
    int sl = i >> 6, d = i & 63;
    tile[sl][d] = qkv[(size_t)(b * 1024 + s0 + sl) * 3072 + 2048 + h * 64 + d];
  }
  __syncthreads();
  for (int i = t; i < 4096; i += 256) {
    int d = i >> 6, sl = i & 63;
    vt[(size_t)(bh * 64 + d) * 1024 + s0 + sl] = tile[sl][d];
  }
}

// ---------------- GEMM: C[m][n] = sum_k A[m][k]*B[n][k] + bias[n] ----------------

template<int OUT_BF16>
__global__ __launch_bounds__(256) void k_gemm(
    const u16* __restrict__ A, const u16* __restrict__ B,
    const float* __restrict__ bias, void* __restrict__ Cout,
    int M, int N, int Kd)
{
  __shared__ u16 Alds[128 * 32];
  __shared__ u16 Blds[128 * 32];
  const int t = threadIdx.x;
  const int lane = t & 63, wid = t >> 6;
  const int wr = wid >> 1, wc = wid & 1;
  const int l15 = lane & 15, lg = lane >> 4;
  const int m0 = blockIdx.y * 128, n0 = blockIdx.x * 128;
  const int trow = t >> 2;
  const int tcol = (t & 3) * 8;

  const f32x4 fzero = {0.f, 0.f, 0.f, 0.f};
  f32x4 acc[4][4];
#pragma unroll
  for (int i = 0; i < 4; i++)
#pragma unroll
    for (int j = 0; j < 4; j++) acc[i][j] = fzero;

  const size_t aoff0 = (size_t)(m0 + trow) * Kd + tcol;
  const size_t aoff1 = (size_t)(m0 + 64 + trow) * Kd + tcol;
  const size_t boff0 = (size_t)(n0 + trow) * Kd + tcol;
  const size_t boff1 = (size_t)(n0 + 64 + trow) * Kd + tcol;
  u16* la0 = Alds + wid * 512;
  u16* la1 = Alds + 2048 + wid * 512;
  u16* lb0 = Blds + wid * 512;
  u16* lb1 = Blds + 2048 + wid * 512;

  for (int k0 = 0; k0 < Kd; k0 += 32) {
    gload16(A + aoff0 + k0, la0);
    gload16(A + aoff1 + k0, la1);
    gload16(B + boff0 + k0, lb0);
    gload16(B + boff1 + k0, lb1);
    __syncthreads();
    bf16x8 av[4], bv[4];
#pragma unroll
    for (int mi = 0; mi < 4; mi++)
      av[mi] = *reinterpret_cast<const bf16x8*>(Alds + (wr * 64 + mi * 16 + l15) * 32 + lg * 8);
#pragma unroll
    for (int ni = 0; ni < 4; ni++)
      bv[ni] = *reinterpret_cast<const bf16x8*>(Blds + (wc * 64 + ni * 16 + l15) * 32 + lg * 8);
#pragma unroll
    for (int mi = 0; mi < 4; mi++)
#pragma unroll
      for (int ni = 0; ni < 4; ni++)
        acc[mi][ni] = mfma16(av[mi], bv[ni], acc[mi][ni]);
    __syncthreads();
  }

#pragma unroll
  for (int mi = 0; mi < 4; mi++) {
#pragma unroll
    for (int ni = 0; ni < 4; ni++) {
      const int col = n0 + wc * 64 + ni * 16 + l15;
      const float bcol = bias[col];
#pragma unroll
      for (int r = 0; r < 4; r++) {
        const int row = m0 + wr * 64 + mi * 16 + lg * 4 + r;
        const float v = acc[mi][ni][r] + bcol;
        if (OUT_BF16) ((u16*)Cout)[(size_t)row * N + col] = f2bf(v);
        else          ((float*)Cout)[(size_t)row * N + col] = v;
      }
    }
  }
}

// ---------------- attention ----------------
// 256 threads = 4 waves, 64 q-rows per block (wave w: rows qb + w*16).
// v2: (a) K/V double-buffered in LDS, ONE __syncthreads per k-tile; prefetch of
//     tile kt+1 issued right after the barrier so it is in flight for the whole
//     compute phase (the compiler's vmcnt(0)-before-barrier drains it at the
//     NEXT barrier = 2-deep pipeline).
// (b) rel band kept in registers: the rel-MFMA output row (lg*4+r) equals the
//     consumer row, so the per-row diagonal shift (15-rowi) is a pure
//     within-16-lane-group column rotation -> ds_bpermute shuffles, no W LDS
//     buffer, no wave_barriers, no W bank conflicts.
// (c) softmax: FULL defer-max (static max 0) as before; single l-reduce at end.

__global__ __launch_bounds__(256, 4) void k_attn(
    const u16* __restrict__ qkv,   // (4096, 3072): Q|K|V
    const u16* __restrict__ vt,    // (64*64, 1024): Vt[bh*64+d][s]
    const u16* __restrict__ relb,  // (1024, 64)
    u16* __restrict__ Oout)        // (4096, 1024)
{
  __shared__ u16 Klds[2][64 * 64];   // 2 x 8 KB, swizzled: byte = row*128 + (cb ^ ((row&7)<<4))
  __shared__ u16 Vlds[2][64 * 64];   // 2 x 8 KB, same swizzle (rows = d)
  __shared__ u16 Plds[4][16 * 64];   // 8 KB, per-wave P (bf16), swizzled rows of 128B

  const int t = threadIdx.x;
  const int lane = t & 63, w = t >> 6;
  const int l15 = lane & 15, lg = lane >> 4;
  const int blk = blockIdx.x;
  const int bh = blk & 63;             // blocks of a bh share an XCD (blk%8 == bh%8)
  const int qbt = 15 - (blk >> 6);     // heavy blocks dispatch first
  const int b = bh >> 4, h = bh & 15;
  const int qb = qbt * 64;
  const int qw = qb + w * 16;

  u16* Pb = Plds[w];
  const f32x4 fzero = {0.f, 0.f, 0.f, 0.f};

  // Q A-fragments, held in registers
  const size_t qrow = (size_t)(b * 1024 + qw + l15) * 3072 + h * 64;
  bf16x8 aQ0 = *reinterpret_cast<const bf16x8*>(qkv + qrow + lg * 8);
  bf16x8 aQ1 = *reinterpret_cast<const bf16x8*>(qkv + qrow + 32 + lg * 8);

  f32x4 oacc[4];
  float l_r[4];
#pragma unroll
  for (int r = 0; r < 4; r++) { oacc[r] = fzero; l_r[r] = 0.f; }

  // staging: thread t stages chunks t and t+256 (16B each) for K and V.
  // dest byte t*16 -> logical (row = t>>3, cb = (t&7)*16); source col byte is
  // inverse-swizzled so LDS holds the swizzled layout with a linear dest.
  const int srow = t >> 3;
  const int scb = ((t & 7) * 16) ^ ((srow & 7) << 4);
  const u16* Ks0 = qkv + (size_t)(b * 1024 + srow) * 3072 + 1024 + h * 64 + (scb >> 1);
  const u16* Ks1 = Ks0 + 32 * 3072;
  const u16* Vs0 = vt + (size_t)(bh * 64 + srow) * 1024 + (scb >> 1);
  const u16* Vs1 = Vs0 + 32 * 1024;

  const int nk = qbt + 1;              // uniform trip count across the 4 waves
  const float SC = 0.125f * 1.44269504f;   // fold 1/sqrt(D) and log2(e)

  // prologue: stage tile 0 into buffer 0
  gload16(Ks0, Klds[0] + t * 8);
  gload16(Ks1, Klds[0] + (t + 256) * 8);
  gload16(Vs0, Vlds[0] + t * 8);
  gload16(Vs1, Vlds[0] + (t + 256) * 8);

  int cur = 0;
  for (int kt = 0; kt < nk; kt++) {
    const int k0 = kt * 64;
    __syncthreads();   // drains vmcnt: buf[cur] ready; all waves done reading buf[cur^1]

    // rel B-fragments for this tile — issued FIRST so waiting on them does not
    // force draining the prefetch (vmcnt waits oldest-first)
    const int rbase = 1008 + k0 - qw;
    bf16x8 rb0[5], rb1[5];
#pragma unroll
    for (int wj = 0; wj < 5; wj++) {
      int rr = rbase + wj * 16 + l15;
      rr = rr < 0 ? 0 : (rr > 1023 ? 1023 : rr);   // clamped rows feed only masked entries
      const u16* rp = relb + rr * 64;
      rb0[wj] = *reinterpret_cast<const bf16x8*>(rp + lg * 8);
      rb1[wj] = *reinterpret_cast<const bf16x8*>(rp + 32 + lg * 8);
    }

    // prefetch next K/V tile into the other buffer (in flight across this tile)
    if (kt + 1 < nk) {
      const int kn = k0 + 64;
      u16* kb = Klds[cur ^ 1];
      u16* vb = Vlds[cur ^ 1];
      gload16(Ks0 + (size_t)kn * 3072, kb + t * 8);
      gload16(Ks1 + (size_t)kn * 3072, kb + (t + 256) * 8);
      gload16(Vs0 + kn, vb + t * 8);
      gload16(Vs1 + kn, vb + (t + 256) * 8);
    }

    // content scores: 16 q x 64 k from swizzled Klds[cur]
    const char* Kb = (const char*)Klds[cur];
    f32x4 sc4[4];
#pragma unroll
    for (int tt = 0; tt < 4; tt++) sc4[tt] = fzero;
#pragma unroll
    for (int tt = 0; tt < 4; tt++) {
      const int row = tt * 16 + l15;
      const int sw = (row & 7) << 4;
      bf16x8 b0 = *reinterpret_cast<const bf16x8*>(Kb + row * 128 + ((lg * 16) ^ sw));
      bf16x8 b1 = *reinterpret_cast<const bf16x8*>(Kb + row * 128 + ((64 + lg * 16) ^ sw));
      sc4[tt] = mfma16(aQ0, b0, sc4[tt]);
      sc4[tt] = mfma16(aQ1, b1, sc4[tt]);
    }

    // rel band in registers: z[wj] rows = lg*4+r, cols = band pos wj*16 + l15
    f32x4 z[5];
#pragma unroll
    for (int wj = 0; wj < 5; wj++) {
      f32x4 zz = fzero;
      zz = mfma16(aQ0, rb0[wj], zz);
      zz = mfma16(aQ1, rb1[wj], zz);
      z[wj] = zz;
    }

    // combine + mask + exp2 (defer-max: static max 0) + P write.
    // Needed band pos p = (15-rowi) + tt*16 + l15 = tt*16 + u, u = l15+15-rowi.
    // Same row (same lg, same reg r) as producer -> within-group rotation.
#pragma unroll
    for (int r = 0; r < 4; r++) {
      const int rowi = lg * 4 + r;
      const int q = qw + rowi;
      const int u = l15 + 15 - rowi;               // in [0,30]
      const int src = (lane & 48) | (u & 15);
      float sz[5];
#pragma unroll
      for (int wj = 0; wj < 5; wj++) sz[wj] = __shfl(z[wj][r], src);
#pragma unroll
      for (int tt = 0; tt < 4; tt++) {
        const int kg = k0 + tt * 16 + l15;
        const float wv = (u & 16) ? sz[tt + 1] : sz[tt];
        const float s = (sc4[tt][r] + wv) * SC;
        const float p = (kg <= q) ? exp2f(s) : 0.f;
        l_r[r] += p;
        const int cb = (32 * tt + 2 * l15) ^ ((rowi & 7) << 4);
        *(u16*)((char*)Pb + rowi * 128 + cb) = f2bf(p);
      }
    }
    __builtin_amdgcn_wave_barrier();
    asm volatile("" ::: "memory");     // order P writes before P reads

    // PV from swizzled Plds (A) and Vlds[cur] (B)
    const char* Vb = (const char*)Vlds[cur];
#pragma unroll
    for (int s = 0; s < 2; s++) {
      const int acb = (s * 64 + lg * 16) ^ ((l15 & 7) << 4);
      bf16x8 aP = *reinterpret_cast<const bf16x8*>((const char*)Pb + l15 * 128 + acb);
#pragma unroll
      for (int dt = 0; dt < 4; dt++) {
        const int vrow = dt * 16 + l15;
        const int vcb = (s * 64 + lg * 16) ^ ((vrow & 7) << 4);
        bf16x8 bV = *reinterpret_cast<const bf16x8*>(Vb + vrow * 128 + vcb);
        oacc[dt] = mfma16(aP, bV, oacc[dt]);
      }
    }
    cur ^= 1;
  }

  // epilogue: one row-sum reduce, scale, store
#pragma unroll
  for (int r = 0; r < 4; r++) {
    float l = l_r[r];
#pragma unroll
    for (int xm = 1; xm < 16; xm <<= 1) l += __shfl_xor(l, xm);
    const float inv = 1.f / l;
    const int q = qw + lg * 4 + r;
#pragma unroll
    for (int dt = 0; dt < 4; dt++)
      Oout[(size_t)(b * 1024 + q) * 1024 + h * 64 + dt * 16 + l15] = f2bf(oacc[dt][r] * inv);
  }
}

// ---------------- launcher ----------------

extern "C" void kernel_launch(void* const* d_in, const int* in_sizes, int n_in,
                              void* d_out, int out_size, void* d_ws, size_t ws_size,
                              hipStream_t stream) {
  const float* x   = (const float*)d_in[0];
  const float* Wq  = (const float*)d_in[1];
  const float* bq  = (const float*)d_in[2];
  const float* Wk  = (const float*)d_in[3];
  const float* bk  = (const float*)d_in[4];
  const float* Wv  = (const float*)d_in[5];
  const float* bv  = (const float*)d_in[6];
  const float* Wo  = (const float*)d_in[7];
  const float* bo  = (const float*)d_in[8];
  const float* rel = (const float*)d_in[9];

  const size_t MB = 1024 * 1024;
  char* ws = (char*)d_ws;
  u16*   xb    = (u16*)(ws);                 // 8MB; reused for attn O after QKV GEMM
  u16*   Wt    = (u16*)(ws + 8 * MB);        // 4096x1024 bf16 (Wq^T|Wk^T|Wv^T|Wo^T)
  u16*   qkvb  = (u16*)(ws + 16 * MB);       // 4096x3072 bf16
  u16*   vtb   = (u16*)(ws + 40 * MB);       // 4096x1024 bf16 (transposed V)
  u16*   relbb = (u16*)(ws + 48 * MB);       // 1024x64 bf16
  float* bqkv  = (float*)(ws + 49 * MB);     // 3072 f32
  u16*   Ob    = xb;

  // 1) conversions
  k_f32_to_bf16<<<4096, 256, 0, stream>>>(x, xb, 1048576);
  k_f32_to_bf16<<<64, 256, 0, stream>>>(rel, relbb, 16384);
  dim3 tg(32, 32);
  k_transpose_w<<<tg, 256, 0, stream>>>(Wq, Wt + 0 * MB);
  k_transpose_w<<<tg, 256, 0, stream>>>(Wk, Wt + 1 * MB);
  k_transpose_w<<<tg, 256, 0, stream>>>(Wv, Wt + 2 * MB);
  k_transpose_w<<<tg, 256, 0, stream>>>(Wo, Wt + 3 * MB);
  k_pack_bias<<<12, 256, 0, stream>>>(bq, bk, bv, bqkv);

  // 2) fused QKV projection
  k_gemm<1><<<dim3(24, 32), 256, 0, stream>>>(xb, Wt, bqkv, qkvb, 4096, 3072, 1024);

  // 3) V transpose for PV B-operand
  k_transpose_v<<<1024, 256, 0, stream>>>(qkvb, vtb);

  // 4) attention (4 waves/block, 64 q-rows/block, K/V double-buffered)
  k_attn<<<1024, 256, 0, stream>>>(qkvb, vtb, relbb, Ob);

  // 5) output projection -> fp32 d_out
  k_gemm<0><<<dim3(8, 32), 256, 0, stream>>>(Ob, Wt + 3 * MB, bo, d_out, 4096, 1024, 1024);
}

// Round 2
// 192.383 us; speedup vs baseline: 1.0794x; 1.0794x over previous
//
#include <hip/hip_runtime.h>

typedef unsigned short u16;
typedef __attribute__((ext_vector_type(8))) __bf16 bf16x8;
typedef __attribute__((ext_vector_type(4))) float f32x4;
typedef __attribute__((ext_vector_type(4))) u16 u16x4;

// ---------------- helpers ----------------

__device__ __forceinline__ u16 f2bf(float f) {
  unsigned u = __float_as_uint(f);
  u += 0x7fff + ((u >> 16) & 1);   // RNE
  return (u16)(u >> 16);
}

__device__ __forceinline__ f32x4 mfma16(bf16x8 a, bf16x8 b, f32x4 c) {
  return __builtin_amdgcn_mfma_f32_16x16x32_bf16(a, b, c, 0, 0, 0);
}

__device__ __forceinline__ void gload16(const void* g, void* l) {
  __builtin_amdgcn_global_load_lds(
      (__attribute__((address_space(1))) unsigned int*)(const_cast<void*>(g)),
      (__attribute__((address_space(3))) unsigned int*)l, 16, 0, 0);
}

// ---------------- small prep kernels ----------------

__global__ void k_f32_to_bf16(const float* __restrict__ in, u16* __restrict__ out, int n4) {
  int i = blockIdx.x * blockDim.x + threadIdx.x;
  if (i < n4) {
    float4 v = reinterpret_cast<const float4*>(in)[i];
    u16x4 o;
    o.x = f2bf(v.x); o.y = f2bf(v.y); o.z = f2bf(v.z); o.w = f2bf(v.w);
    reinterpret_cast<u16x4*>(out)[i] = o;
  }
}

// Wt[n][k] = W[k][n], fp32 -> bf16. 32x32 tiles.
__global__ void k_transpose_w(const float* __restrict__ in, u16* __restrict__ out) {
  __shared__ float tile[32][33];
  const int r0 = blockIdx.y * 32, c0 = blockIdx.x * 32;
  const int t = threadIdx.x;
  for (int i = t; i < 1024; i += 256) {
    int r = i >> 5, c = i & 31;
    tile[r][c] = in[(size_t)(r0 + r) * 1024 + c0 + c];
  }
  __syncthreads();
  for (int i = t; i < 1024; i += 256) {
    int r = i >> 5, c = i & 31;
    out[(size_t)(c0 + r) * 1024 + r0 + c] = f2bf(tile[c][r]);
  }
}

__global__ void k_pack_bias(const float* __restrict__ bq, const float* __restrict__ bk,
                            const float* __restrict__ bv, float* __restrict__ out) {
  int i = blockIdx.x * 256 + threadIdx.x;
  if (i < 3072) out[i] = (i < 1024) ? bq[i] : (i < 2048 ? bk[i - 1024] : bv[i - 2048]);
}

// Vt[(b*16+h)*64 + d][s] = QKV[(b*1024+s)*3072 + 2048 + h*64 + d]
__global__ void k_transpose_v(const u16* __restrict__ qkv, u16* __restrict__ vt) {
  __shared__ u16 tile[64][65];
  const int bh = blockIdx.x >> 4;     // b*16+h
  const int st = blockIdx.x & 15;
  const int b = bh >> 4, h = bh & 15;
  const int s0 = st * 64;
  const int t = threadIdx.x;
  for (int i = t; i < 4096; i += 256) {
    int sl = i >> 6, d = i & 63;
    tile[sl][d] = qkv[(size_t)(b * 1024 + s0 + sl) * 3072 + 2048 + h * 64 + d];
  }
  __syncthreads();
  for (int i = t; i < 4096; i += 256) {
    int d = i >> 6, sl = i & 63;
    vt[(size_t)(bh * 64 + d) * 1024 + s0 + sl] = tile[sl][d];
  }
}

// ---------------- GEMM: C[m][n] = sum_k A[m][k]*B[n][k] + bias[n] ----------------

template<int OUT_BF16>
__global__ __launch_bounds__(256) void k_gemm(
    const u16* __restrict__ A, const u16* __restrict__ B,
    const float* __restrict__ bias, void* __restrict__ Cout,
    int M, int N, int Kd)
{
  __shared__ u16 Alds[128 * 32];
  __shared__ u16 Blds[128 * 32];
  const int t = threadIdx.x;
  const int lane = t & 63, wid = t >> 6;
  const int wr = wid >> 1, wc = wid & 1;
  const int l15 = lane & 15, lg = lane >> 4;
  const int m0 = blockIdx.y * 128, n0 = blockIdx.x * 128;
  const int trow = t >> 2;
  const int tcol = (t & 3) * 8;

  const f32x4 fzero = {0.f, 0.f, 0.f, 0.f};
  f32x4 acc[4][4];
#pragma unroll
  for (int i = 0; i < 4; i++)
#pragma unroll
    for (int j = 0; j < 4; j++) acc[i][j] = fzero;

  const size_t aoff0 = (size_t)(m0 + trow) * Kd + tcol;
  const size_t aoff1 = (size_t)(m0 + 64 + trow) * Kd + tcol;
  const size_t boff0 = (size_t)(n0 + trow) * Kd + tcol;
  const size_t boff1 = (size_t)(n0 + 64 + trow) * Kd + tcol;
  u16* la0 = Alds + wid * 512;
  u16* la1 = Alds + 2048 + wid * 512;
  u16* lb0 = Blds + wid * 512;
  u16* lb1 = Blds + 2048 + wid * 512;

  for (int k0 = 0; k0 < Kd; k0 += 32) {
    gload16(A + aoff0 + k0, la0);
    gload16(A + aoff1 + k0, la1);
    gload16(B + boff0 + k0, lb0);
    gload16(B + boff1 + k0, lb1);
    __syncthreads();
    bf16x8 av[4], bv[4];
#pragma unroll
    for (int mi = 0; mi < 4; mi++)
      av[mi] = *reinterpret_cast<const bf16x8*>(Alds + (wr * 64 + mi * 16 + l15) * 32 + lg * 8);
#pragma unroll
    for (int ni = 0; ni < 4; ni++)
      bv[ni] = *reinterpret_cast<const bf16x8*>(Blds + (wc * 64 + ni * 16 + l15) * 32 + lg * 8);
#pragma unroll
    for (int mi = 0; mi < 4; mi++)
#pragma unroll
      for (int ni = 0; ni < 4; ni++)
        acc[mi][ni] = mfma16(av[mi], bv[ni], acc[mi][ni]);
    __syncthreads();
  }

#pragma unroll
  for (int mi = 0; mi < 4; mi++) {
#pragma unroll
    for (int ni = 0; ni < 4; ni++) {
      const int col = n0 + wc * 64 + ni * 16 + l15;
      const float bcol = bias[col];
#pragma unroll
      for (int r = 0; r < 4; r++) {
        const int row = m0 + wr * 64 + mi * 16 + lg * 4 + r;
        const float v = acc[mi][ni][r] + bcol;
        if (OUT_BF16) ((u16*)Cout)[(size_t)row * N + col] = f2bf(v);
        else          ((float*)Cout)[(size_t)row * N + col] = v;
      }
    }
  }
}

// ---------------- attention ----------------
// v3 = round-0 proven structure (single-buffered K/V, stage -> sync -> compute,
// two __syncthreads per k-tile) + two validated changes:
//  (a) rel band combined in REGISTERS via within-group shuffle (round 1 proved
//      this is correct and bank-conflict-free; removes the W LDS buffer and
//      its 2.5M conflict cycles, and 12KB of LDS -> 24KB total).
//  (b) load-balanced q-tile mapping: the 16 q-tile groups are assigned so that
//      each residue class mod 4 (the groups that co-reside on one CU under
//      round-robin dispatch) has equal total work (sum nk = 34), killing the
//      28-vs-40 drain imbalance of the linear heavy-first mapping. Heavy
//      blocks still dispatch first; bh = blk&63 (XCD locality) unchanged.
// NO cross-iteration vmem pipelining: round 1 showed that register rel-loads +
// gload_lds prefetch in one vmcnt queue forces a mid-iteration vmcnt(0) drain.

__global__ __launch_bounds__(256, 4) void k_attn(
    const u16* __restrict__ qkv,   // (4096, 3072): Q|K|V
    const u16* __restrict__ vt,    // (64*64, 1024): Vt[bh*64+d][s]
    const u16* __restrict__ relb,  // (1024, 64)
    u16* __restrict__ Oout)        // (4096, 1024)
{
  __shared__ u16 Klds[64 * 64];      // 8 KB, swizzled: byte = row*128 + (cb ^ ((row&7)<<4))
  __shared__ u16 Vlds[64 * 64];      // 8 KB, same swizzle (rows = d)
  __shared__ u16 Plds[4][16 * 64];   // 8 KB, per-wave P (bf16), swizzled rows of 128B

  const int t = threadIdx.x;
  const int lane = t & 63, w = t >> 6;
  const int l15 = lane & 15, lg = lane >> 4;
  const int blk = blockIdx.x;
  const int bh = blk & 63;             // blocks of a bh share an XCD (blk%8 == bh%8)
  // balanced q-tile mapping: groups {g, g+4, g+8, g+12} land on the same CU;
  // qbt per quarter j: {15-r, 8+r, 7-r, r} -> per-CU sum(nk) == 34 for all r.
  const int g = blk >> 6;
  const int jq = g >> 2, rq = g & 3;
  const int qbt = (jq == 0) ? (15 - rq) : (jq == 1) ? (8 + rq) : (jq == 2) ? (7 - rq) : rq;
  const int b = bh >> 4, h = bh & 15;
  const int qb = qbt * 64;
  const int qw = qb + w * 16;

  u16* Pb = Plds[w];
  const f32x4 fzero = {0.f, 0.f, 0.f, 0.f};

  // Q A-fragments, held in registers
  const size_t qrow = (size_t)(b * 1024 + qw + l15) * 3072 + h * 64;
  bf16x8 aQ0 = *reinterpret_cast<const bf16x8*>(qkv + qrow + lg * 8);
  bf16x8 aQ1 = *reinterpret_cast<const bf16x8*>(qkv + qrow + 32 + lg * 8);

  f32x4 oacc[4];
  float l_r[4];
#pragma unroll
  for (int r = 0; r < 4; r++) { oacc[r] = fzero; l_r[r] = 0.f; }

  // staging: thread t stages chunks t and t+256 (16B each) for K and V.
  // dest byte t*16 -> logical (row = t>>3, cb = (t&7)*16); source col byte is
  // inverse-swizzled so LDS holds the swizzled layout with a linear dest.
  const int srow = t >> 3;
  const int scb = ((t & 7) * 16) ^ ((srow & 7) << 4);
  const u16* Ks0 = qkv + (size_t)(b * 1024 + srow) * 3072 + 1024 + h * 64 + (scb >> 1);
  const u16* Ks1 = Ks0 + 32 * 3072;
  const u16* Vs0 = vt + (size_t)(bh * 64 + srow) * 1024 + (scb >> 1);
  const u16* Vs1 = Vs0 + 32 * 1024;
  u16* Kd0 = Klds + t * 8;  u16* Kd1 = Klds + (t + 256) * 8;
  u16* Vd0 = Vlds + t * 8;  u16* Vd1 = Vlds + (t + 256) * 8;

  const int nk = qbt + 1;              // uniform trip count across the 4 waves
  const float SC = 0.125f * 1.44269504f;   // fold 1/sqrt(D) and log2(e)

  for (int kt = 0; kt < nk; kt++) {
    const int k0 = kt * 64;
    gload16(Ks0 + (size_t)k0 * 3072, Kd0);
    gload16(Ks1 + (size_t)k0 * 3072, Kd1);
    gload16(Vs0 + k0, Vd0);
    gload16(Vs1 + k0, Vd1);
    __syncthreads();   // drains vmcnt for all waves; K/V tile ready

    // rel B-fragments issued up front: the only outstanding vmem during the QK
    // phase, whose ds_reads + 8 MFMAs hide most of their (L2-hot) latency.
    const int rbase = 1008 + k0 - qw;
    bf16x8 rb0[5], rb1[5];
#pragma unroll
    for (int wj = 0; wj < 5; wj++) {
      int rr = rbase + wj * 16 + l15;
      rr = rr < 0 ? 0 : (rr > 1023 ? 1023 : rr);   // clamped rows feed only masked entries
      const u16* rp = relb + rr * 64;
      rb0[wj] = *reinterpret_cast<const bf16x8*>(rp + lg * 8);
      rb1[wj] = *reinterpret_cast<const bf16x8*>(rp + 32 + lg * 8);
    }

    // content scores: 16 q x 64 k from swizzled Klds
    f32x4 sc4[4];
#pragma unroll
    for (int tt = 0; tt < 4; tt++) sc4[tt] = fzero;
#pragma unroll
    for (int tt = 0; tt < 4; tt++) {
      const int row = tt * 16 + l15;
      const int sw = (row & 7) << 4;
      bf16x8 b0 = *reinterpret_cast<const bf16x8*>((const char*)Klds + row * 128 + ((lg * 16) ^ sw));
      bf16x8 b1 = *reinterpret_cast<const bf16x8*>((const char*)Klds + row * 128 + ((64 + lg * 16) ^ sw));
      sc4[tt] = mfma16(aQ0, b0, sc4[tt]);
      sc4[tt] = mfma16(aQ1, b1, sc4[tt]);
    }

    // rel band in registers: z[wj] rows = lg*4+r, cols = band pos wj*16 + l15
    f32x4 z[5];
#pragma unroll
    for (int wj = 0; wj < 5; wj++) {
      f32x4 zz = fzero;
      zz = mfma16(aQ0, rb0[wj], zz);
      zz = mfma16(aQ1, rb1[wj], zz);
      z[wj] = zz;
    }

    // combine + mask + exp2 (defer-max: static max 0) + P write.
    // Needed band pos p = (15-rowi) + tt*16 + l15 = tt*16 + u, u = l15+15-rowi.
    // Same row (same lg, same reg r) as producer -> within-16-group rotation.
#pragma unroll
    for (int r = 0; r < 4; r++) {
      const int rowi = lg * 4 + r;
      const int q = qw + rowi;
      const int u = l15 + 15 - rowi;               // in [0,30]
      const int src = (lane & 48) | (u & 15);
      float sz[5];
#pragma unroll
      for (int wj = 0; wj < 5; wj++) sz[wj] = __shfl(z[wj][r], src);
#pragma unroll
      for (int tt = 0; tt < 4; tt++) {
        const int kg = k0 + tt * 16 + l15;
        const float wv = (u & 16) ? sz[tt + 1] : sz[tt];
        const float s = (sc4[tt][r] + wv) * SC;
        const float p = (kg <= q) ? exp2f(s) : 0.f;
        l_r[r] += p;
        const int cb = (32 * tt + 2 * l15) ^ ((rowi & 7) << 4);
        *(u16*)((char*)Pb + rowi * 128 + cb) = f2bf(p);
      }
    }
    __builtin_amdgcn_wave_barrier();
    asm volatile("" ::: "memory");     // order P writes before P reads

    // PV from swizzled Plds (A) and Vlds (B)
#pragma unroll
    for (int s = 0; s < 2; s++) {
      const int acb = (s * 64 + lg * 16) ^ ((l15 & 7) << 4);
      bf16x8 aP = *reinterpret_cast<const bf16x8*>((const char*)Pb + l15 * 128 + acb);
#pragma unroll
      for (int dt = 0; dt < 4; dt++) {
        const int vrow = dt * 16 + l15;
        const int vcb = (s * 64 + lg * 16) ^ ((vrow & 7) << 4);
        bf16x8 bV = *reinterpret_cast<const bf16x8*>((const char*)Vlds + vrow * 128 + vcb);
        oacc[dt] = mfma16(aP, bV, oacc[dt]);
      }
    }
    __syncthreads();   // all waves done with K/V/P before restaging
  }

  // epilogue: one row-sum reduce, scale, store
#pragma unroll
  for (int r = 0; r < 4; r++) {
    float l = l_r[r];
#pragma unroll
    for (int xm = 1; xm < 16; xm <<= 1) l += __shfl_xor(l, xm);
    const float inv = 1.f / l;
    const int q = qw + lg * 4 + r;
#pragma unroll
    for (int dt = 0; dt < 4; dt++)
      Oout[(size_t)(b * 1024 + q) * 1024 + h * 64 + dt * 16 + l15] = f2bf(oacc[dt][r] * inv);
  }
}

// ---------------- launcher ----------------

extern "C" void kernel_launch(void* const* d_in, const int* in_sizes, int n_in,
                              void* d_out, int out_size, void* d_ws, size_t ws_size,
                              hipStream_t stream) {
  const float* x   = (const float*)d_in[0];
  const float* Wq  = (const float*)d_in[1];
  const float* bq  = (const float*)d_in[2];
  const float* Wk  = (const float*)d_in[3];
  const float* bk  = (const float*)d_in[4];
  const float* Wv  = (const float*)d_in[5];
  const float* bv  = (const float*)d_in[6];
  const float* Wo  = (const float*)d_in[7];
  const float* bo  = (const float*)d_in[8];
  const float* rel = (const float*)d_in[9];

  const size_t MB = 1024 * 1024;
  char* ws = (char*)d_ws;
  u16*   xb    = (u16*)(ws);                 // 8MB; reused for attn O after QKV GEMM
  u16*   Wt    = (u16*)(ws + 8 * MB);        // 4096x1024 bf16 (Wq^T|Wk^T|Wv^T|Wo^T)
  u16*   qkvb  = (u16*)(ws + 16 * MB);       // 4096x3072 bf16
  u16*   vtb   = (u16*)(ws + 40 * MB);       // 4096x1024 bf16 (transposed V)
  u16*   relbb = (u16*)(ws + 48 * MB);       // 1024x64 bf16
  float* bqkv  = (float*)(ws + 49 * MB);     // 3072 f32
  u16*   Ob    = xb;

  // 1) conversions
  k_f32_to_bf16<<<4096, 256, 0, stream>>>(x, xb, 1048576);
  k_f32_to_bf16<<<64, 256, 0, stream>>>(rel, relbb, 16384);
  dim3 tg(32, 32);
  k_transpose_w<<<tg, 256, 0, stream>>>(Wq, Wt + 0 * MB);
  k_transpose_w<<<tg, 256, 0, stream>>>(Wk, Wt + 1 * MB);
  k_transpose_w<<<tg, 256, 0, stream>>>(Wv, Wt + 2 * MB);
  k_transpose_w<<<tg, 256, 0, stream>>>(Wo, Wt + 3 * MB);
  k_pack_bias<<<12, 256, 0, stream>>>(bq, bk, bv, bqkv);

  // 2) fused QKV projection
  k_gemm<1><<<dim3(24, 32), 256, 0, stream>>>(xb, Wt, bqkv, qkvb, 4096, 3072, 1024);

  // 3) V transpose for PV B-operand
  k_transpose_v<<<1024, 256, 0, stream>>>(qkvb, vtb);

  // 4) attention (4 waves/block, 64 q-rows/block, balanced q-tile mapping)
  k_attn<<<1024, 256, 0, stream>>>(qkvb, vtb, relbb, Ob);

  // 5) output projection -> fp32 d_out
  k_gemm<0><<<dim3(8, 32), 256, 0, stream>>>(Ob, Wt + 3 * MB, bo, d_out, 4096, 1024, 1024);
}

// Round 3
// 150.218 us; speedup vs baseline: 1.3823x; 1.2807x over previous
//
#include <hip/hip_runtime.h>

typedef unsigned short u16;
typedef __attribute__((ext_vector_type(8))) __bf16 bf16x8;
typedef __attribute__((ext_vector_type(4))) float f32x4;
typedef __attribute__((ext_vector_type(4))) u16 u16x4;

// ---------------- helpers ----------------

__device__ __forceinline__ u16 f2bf(float f) {
  unsigned u = __float_as_uint(f);
  u += 0x7fff + ((u >> 16) & 1);   // RNE
  return (u16)(u >> 16);
}

__device__ __forceinline__ f32x4 mfma16(bf16x8 a, bf16x8 b, f32x4 c) {
  return __builtin_amdgcn_mfma_f32_16x16x32_bf16(a, b, c, 0, 0, 0);
}

__device__ __forceinline__ void gload16(const void* g, void* l) {
  __builtin_amdgcn_global_load_lds(
      (__attribute__((address_space(1))) unsigned int*)(const_cast<void*>(g)),
      (__attribute__((address_space(3))) unsigned int*)l, 16, 0, 0);
}

// ---------------- prep kernels (fused) ----------------

__global__ void k_f32_to_bf16(const float* __restrict__ in, u16* __restrict__ out, int n4) {
  int i = blockIdx.x * blockDim.x + threadIdx.x;
  if (i < n4) {
    float4 v = reinterpret_cast<const float4*>(in)[i];
    u16x4 o;
    o.x = f2bf(v.x); o.y = f2bf(v.y); o.z = f2bf(v.z); o.w = f2bf(v.w);
    reinterpret_cast<u16x4*>(out)[i] = o;
  }
}

// rel f32->bf16 (blocks 0..63) + bias pack (blocks 64..75) in one launch
__global__ void k_prep_small(const float* __restrict__ rel, u16* __restrict__ relb,
                             const float* __restrict__ bq, const float* __restrict__ bk,
                             const float* __restrict__ bv, float* __restrict__ bias) {
  const int bx = blockIdx.x, t = threadIdx.x;
  if (bx < 64) {
    int i = bx * 256 + t;          // 16384 float4 chunks
    float4 v = reinterpret_cast<const float4*>(rel)[i];
    u16x4 o;
    o.x = f2bf(v.x); o.y = f2bf(v.y); o.z = f2bf(v.z); o.w = f2bf(v.w);
    reinterpret_cast<u16x4*>(relb)[i] = o;
  } else {
    int i = (bx - 64) * 256 + t;
    if (i < 3072) bias[i] = (i < 1024) ? bq[i] : (i < 2048 ? bk[i - 1024] : bv[i - 2048]);
  }
}

// Wt[n][k] = W[k][n], fp32 -> bf16, all four weights in one launch (grid.z = 4)
__global__ void k_transpose_w4(const float* __restrict__ W0, const float* __restrict__ W1,
                               const float* __restrict__ W2, const float* __restrict__ W3,
                               u16* __restrict__ outbase) {
  __shared__ float tile[32][33];
  const int z = blockIdx.z;
  const float* in = (z == 0) ? W0 : (z == 1) ? W1 : (z == 2) ? W2 : W3;
  u16* out = outbase + (size_t)z * 1024 * 1024;
  const int r0 = blockIdx.y * 32, c0 = blockIdx.x * 32;
  const int t = threadIdx.x;
  for (int i = t; i < 1024; i += 256) {
    int r = i >> 5, c = i & 31;
    tile[r][c] = in[(size_t)(r0 + r) * 1024 + c0 + c];
  }
  __syncthreads();
  for (int i = t; i < 1024; i += 256) {
    int r = i >> 5, c = i & 31;
    out[(size_t)(c0 + r) * 1024 + r0 + c] = f2bf(tile[c][r]);
  }
}

// ---------------- GEMM: C[m][n] = sum_k A[m][k]*B[n][k] + bias[n] ----------------
// MODE 0: fp32 output. MODE 2: bf16 output, and cols >= 2048 (the V block of the
// fused QKV GEMM) are routed to Vaux in transposed layout
// Vaux[(b*1024 + (col-2048))*1024 + s] (s = row&1023, b = row>>10), replacing the
// separate k_transpose_v kernel; the V region of C is never written (never read).

template<int MODE>
__global__ __launch_bounds__(256) void k_gemm(
    const u16* __restrict__ A, const u16* __restrict__ B,
    const float* __restrict__ bias, void* __restrict__ Cout,
    u16* __restrict__ Vaux, int M, int N, int Kd)
{
  __shared__ u16 Alds[128 * 32];
  __shared__ u16 Blds[128 * 32];
  const int t = threadIdx.x;
  const int lane = t & 63, wid = t >> 6;
  const int wr = wid >> 1, wc = wid & 1;
  const int l15 = lane & 15, lg = lane >> 4;
  const int m0 = blockIdx.y * 128, n0 = blockIdx.x * 128;
  const int trow = t >> 2;
  const int tcol = (t & 3) * 8;

  const f32x4 fzero = {0.f, 0.f, 0.f, 0.f};
  f32x4 acc[4][4];
#pragma unroll
  for (int i = 0; i < 4; i++)
#pragma unroll
    for (int j = 0; j < 4; j++) acc[i][j] = fzero;

  const size_t aoff0 = (size_t)(m0 + trow) * Kd + tcol;
  const size_t aoff1 = (size_t)(m0 + 64 + trow) * Kd + tcol;
  const size_t boff0 = (size_t)(n0 + trow) * Kd + tcol;
  const size_t boff1 = (size_t)(n0 + 64 + trow) * Kd + tcol;
  u16* la0 = Alds + wid * 512;
  u16* la1 = Alds + 2048 + wid * 512;
  u16* lb0 = Blds + wid * 512;
  u16* lb1 = Blds + 2048 + wid * 512;

  for (int k0 = 0; k0 < Kd; k0 += 32) {
    gload16(A + aoff0 + k0, la0);
    gload16(A + aoff1 + k0, la1);
    gload16(B + boff0 + k0, lb0);
    gload16(B + boff1 + k0, lb1);
    __syncthreads();
    bf16x8 av[4], bv[4];
#pragma unroll
    for (int mi = 0; mi < 4; mi++)
      av[mi] = *reinterpret_cast<const bf16x8*>(Alds + (wr * 64 + mi * 16 + l15) * 32 + lg * 8);
#pragma unroll
    for (int ni = 0; ni < 4; ni++)
      bv[ni] = *reinterpret_cast<const bf16x8*>(Blds + (wc * 64 + ni * 16 + l15) * 32 + lg * 8);
#pragma unroll
    for (int mi = 0; mi < 4; mi++)
#pragma unroll
      for (int ni = 0; ni < 4; ni++)
        acc[mi][ni] = mfma16(av[mi], bv[ni], acc[mi][ni]);
    __syncthreads();
  }

#pragma unroll
  for (int mi = 0; mi < 4; mi++) {
#pragma unroll
    for (int ni = 0; ni < 4; ni++) {
      const int col = n0 + wc * 64 + ni * 16 + l15;
      const float bcol = bias[col];
#pragma unroll
      for (int r = 0; r < 4; r++) {
        const int row = m0 + wr * 64 + mi * 16 + lg * 4 + r;
        const float v = acc[mi][ni][r] + bcol;
        if (MODE == 0) {
          ((float*)Cout)[(size_t)row * N + col] = v;
        } else {
          if (col < 2048) {
            ((u16*)Cout)[(size_t)row * N + col] = f2bf(v);
          } else {
            const int bb = row >> 10, ss = row & 1023;
            Vaux[((size_t)bb * 1024 + (col - 2048)) * 1024 + ss] = f2bf(v);
          }
        }
      }
    }
  }
}

// ---------------- attention ----------------
// v4 = round-0 proven structure RESTORED verbatim (single-buffered K/V,
// stage -> sync -> compute -> sync; rel fragments loaded INSIDE the wj loop and
// consumed immediately — short vmem live ranges, no spills; W band via LDS).
// Two local deltas only:
//  (a) balanced q-tile mapping: co-resident CU sets {g,g+4,g+8,g+12} each sum
//      to nk = 34 (was 28..40) — kills the drain-tail imbalance.
//  (b) Sbuf stride 80 -> 84 floats: W-band writes become 2-way (free) bank
//      aliasing, reads drop 4-way -> <=3-way. (Round-0 had 2.5M conflict cy.)
// Round 1/2 lesson: do NOT hoist rel loads into long-lived register arrays and
// do NOT share the vmcnt queue between register loads and gload_lds prefetch.

__global__ __launch_bounds__(256, 4) void k_attn(
    const u16* __restrict__ qkv,   // (4096, 3072): Q|K|V
    const u16* __restrict__ vt,    // (64*64, 1024): Vt[bh*64+d][s]
    const u16* __restrict__ relb,  // (1024, 64)
    u16* __restrict__ Oout)        // (4096, 1024)
{
  __shared__ u16 Klds[64 * 64];        // 8 KB, swizzled: byte = row*128 + (cb ^ ((row&7)<<4))
  __shared__ u16 Vlds[64 * 64];        // 8 KB, same swizzle (rows = d)
  __shared__ float Sbuf[4][16 * 84];   // 21 KB, per-wave: W band f32 (stride 84); P (bf16) aliases base

  const int t = threadIdx.x;
  const int lane = t & 63, w = t >> 6;
  const int l15 = lane & 15, lg = lane >> 4;
  const int blk = blockIdx.x;
  const int bh = blk & 63;             // blocks of a bh share an XCD (blk%8 == bh%8)
  // balanced q-tile mapping: groups {g, g+4, g+8, g+12} co-reside on one CU;
  // qbt per quarter j: {15-r, 8+r, 7-r, r} -> per-CU sum(nk) == 34 for all r.
  const int g = blk >> 6;
  const int jq = g >> 2, rq = g & 3;
  const int qbt = (jq == 0) ? (15 - rq) : (jq == 1) ? (8 + rq) : (jq == 2) ? (7 - rq) : rq;
  const int b = bh >> 4, h = bh & 15;
  const int qb = qbt * 64;
  const int qw = qb + w * 16;

  float* Wb = Sbuf[w];
  u16* Pb = (u16*)Sbuf[w];             // aliases Wb; ordering via wave_barrier fences

  const f32x4 fzero = {0.f, 0.f, 0.f, 0.f};

  // Q A-fragments, held in registers
  const size_t qrow = (size_t)(b * 1024 + qw + l15) * 3072 + h * 64;
  bf16x8 aQ0 = *reinterpret_cast<const bf16x8*>(qkv + qrow + lg * 8);
  bf16x8 aQ1 = *reinterpret_cast<const bf16x8*>(qkv + qrow + 32 + lg * 8);

  f32x4 oacc[4];
  float l_r[4];
#pragma unroll
  for (int r = 0; r < 4; r++) { oacc[r] = fzero; l_r[r] = 0.f; }

  // staging: thread t stages chunks t and t+256 (16B each) for K and V.
  // dest byte t*16 -> logical (row = t>>3, cb = (t&7)*16); source col byte is
  // inverse-swizzled so LDS holds the swizzled layout with a linear dest.
  const int srow = t >> 3;
  const int scb = ((t & 7) * 16) ^ ((srow & 7) << 4);
  const u16* Ks0 = qkv + (size_t)(b * 1024 + srow) * 3072 + 1024 + h * 64 + (scb >> 1);
  const u16* Ks1 = Ks0 + 32 * 3072;
  const u16* Vs0 = vt + (size_t)(bh * 64 + srow) * 1024 + (scb >> 1);
  const u16* Vs1 = Vs0 + 32 * 1024;
  u16* Kd0 = Klds + t * 8;  u16* Kd1 = Klds + (t + 256) * 8;
  u16* Vd0 = Vlds + t * 8;  u16* Vd1 = Vlds + (t + 256) * 8;

  const int nk = qbt + 1;              // uniform trip count across the 4 waves
  const float SC = 0.125f * 1.44269504f;   // fold 1/sqrt(D) and log2(e)

  for (int kt = 0; kt < nk; kt++) {
    const int k0 = kt * 64;
    gload16(Ks0 + (size_t)k0 * 3072, Kd0);
    gload16(Ks1 + (size_t)k0 * 3072, Kd1);
    gload16(Vs0 + k0, Vd0);
    gload16(Vs1 + k0, Vd1);
    __syncthreads();   // drains vmcnt for all waves; K/V tile ready

    // content scores: 16 q x 64 k from swizzled Klds
    f32x4 sc4[4];
#pragma unroll
    for (int tt = 0; tt < 4; tt++) sc4[tt] = fzero;
#pragma unroll
    for (int tt = 0; tt < 4; tt++) {
      const int row = tt * 16 + l15;
      const int sw = (row & 7) << 4;
      bf16x8 b0 = *reinterpret_cast<const bf16x8*>((const char*)Klds + row * 128 + ((lg * 16) ^ sw));
      bf16x8 b1 = *reinterpret_cast<const bf16x8*>((const char*)Klds + row * 128 + ((64 + lg * 16) ^ sw));
      sc4[tt] = mfma16(aQ0, b0, sc4[tt]);
      sc4[tt] = mfma16(aQ1, b1, sc4[tt]);
    }

    // rel band: W[q][j] = Q[q]·rel[rbase+j], j in [0,80); direct global (L2-hot)
    const int rbase = 1008 + k0 - qw;
#pragma unroll
    for (int wj = 0; wj < 5; wj++) {
      int rr = rbase + wj * 16 + l15;
      rr = rr < 0 ? 0 : (rr > 1023 ? 1023 : rr);   // clamped rows feed only masked entries
      const u16* rp = relb + rr * 64;
      bf16x8 b0 = *reinterpret_cast<const bf16x8*>(rp + lg * 8);
      bf16x8 b1 = *reinterpret_cast<const bf16x8*>(rp + 32 + lg * 8);
      f32x4 z = fzero;
      z = mfma16(aQ0, b0, z);
      z = mfma16(aQ1, b1, z);
#pragma unroll
      for (int r = 0; r < 4; r++)
        Wb[(lg * 4 + r) * 84 + wj * 16 + l15] = z[r];
    }
    __builtin_amdgcn_wave_barrier();

    // combine + mask + exp2 (defer-max: static max 0); per-lane l partials
    float pvv[4][4];
#pragma unroll
    for (int r = 0; r < 4; r++) {
      const int rowi = lg * 4 + r;
      const int q = qw + rowi;
      const float* wrow = Wb + rowi * 84 + (15 - rowi);
#pragma unroll
      for (int tt = 0; tt < 4; tt++) {
        const int kg = k0 + tt * 16 + l15;
        float s = (sc4[tt][r] + wrow[tt * 16 + l15]) * SC;
        s = (kg <= q) ? s : -1e30f;
        float p = exp2f(s);
        pvv[tt][r] = p;
        l_r[r] += p;
      }
    }
    __builtin_amdgcn_wave_barrier();
    asm volatile("" ::: "memory");     // order W-reads before aliased P-writes

    // P -> LDS bf16, swizzled rows of 128B
#pragma unroll
    for (int tt = 0; tt < 4; tt++)
#pragma unroll
      for (int r = 0; r < 4; r++) {
        const int rowi = lg * 4 + r;
        const int cb = (32 * tt + 2 * l15) ^ ((rowi & 7) << 4);
        *(u16*)((char*)Pb + rowi * 128 + cb) = f2bf(pvv[tt][r]);
      }
    __builtin_amdgcn_wave_barrier();

    // PV from swizzled Plds (A) and Vlds (B)
#pragma unroll
    for (int s = 0; s < 2; s++) {
      const int acb = (s * 64 + lg * 16) ^ ((l15 & 7) << 4);
      bf16x8 aP = *reinterpret_cast<const bf16x8*>((const char*)Pb + l15 * 128 + acb);
#pragma unroll
      for (int dt = 0; dt < 4; dt++) {
        const int vrow = dt * 16 + l15;
        const int vcb = (s * 64 + lg * 16) ^ ((vrow & 7) << 4);
        bf16x8 bV = *reinterpret_cast<const bf16x8*>((const char*)Vlds + vrow * 128 + vcb);
        oacc[dt] = mfma16(aP, bV, oacc[dt]);
      }
    }
    __syncthreads();   // all waves done with K/V/P before restaging
  }

  // epilogue: one row-sum reduce, scale, store
#pragma unroll
  for (int r = 0; r < 4; r++) {
    float l = l_r[r];
#pragma unroll
    for (int xm = 1; xm < 16; xm <<= 1) l += __shfl_xor(l, xm);
    const float inv = 1.f / l;
    const int q = qw + lg * 4 + r;
#pragma unroll
    for (int dt = 0; dt < 4; dt++)
      Oout[(size_t)(b * 1024 + q) * 1024 + h * 64 + dt * 16 + l15] = f2bf(oacc[dt][r] * inv);
  }
}

// ---------------- launcher ----------------

extern "C" void kernel_launch(void* const* d_in, const int* in_sizes, int n_in,
                              void* d_out, int out_size, void* d_ws, size_t ws_size,
                              hipStream_t stream) {
  const float* x   = (const float*)d_in[0];
  const float* Wq  = (const float*)d_in[1];
  const float* bq  = (const float*)d_in[2];
  const float* Wk  = (const float*)d_in[3];
  const float* bk  = (const float*)d_in[4];
  const float* Wv  = (const float*)d_in[5];
  const float* bv  = (const float*)d_in[6];
  const float* Wo  = (const float*)d_in[7];
  const float* bo  = (const float*)d_in[8];
  const float* rel = (const float*)d_in[9];

  const size_t MB = 1024 * 1024;
  char* ws = (char*)d_ws;
  u16*   xb    = (u16*)(ws);                 // 8MB; reused for attn O after QKV GEMM
  u16*   Wt    = (u16*)(ws + 8 * MB);        // 4096x1024 bf16 (Wq^T|Wk^T|Wv^T|Wo^T)
  u16*   qkvb  = (u16*)(ws + 16 * MB);       // 4096x3072 bf16 (V region unused)
  u16*   vtb   = (u16*)(ws + 40 * MB);       // 4096x1024 bf16 (transposed V)
  u16*   relbb = (u16*)(ws + 48 * MB);       // 1024x64 bf16
  float* bqkv  = (float*)(ws + 49 * MB);     // 3072 f32
  u16*   Ob    = xb;

  // 1) conversions + packs (fused: 10 launches -> 6)
  k_f32_to_bf16<<<4096, 256, 0, stream>>>(x, xb, 1048576);
  k_prep_small<<<76, 256, 0, stream>>>(rel, relbb, bq, bk, bv, bqkv);
  k_transpose_w4<<<dim3(32, 32, 4), 256, 0, stream>>>(Wq, Wk, Wv, Wo, Wt);

  // 2) fused QKV projection; V block written directly transposed into vtb
  k_gemm<2><<<dim3(24, 32), 256, 0, stream>>>(xb, Wt, bqkv, qkvb, vtb, 4096, 3072, 1024);

  // 3) attention (4 waves/block, 64 q-rows/block, balanced q-tile mapping)
  k_attn<<<1024, 256, 0, stream>>>(qkvb, vtb, relbb, Ob);

  // 4) output projection -> fp32 d_out
  k_gemm<0><<<dim3(8, 32), 256, 0, stream>>>(Ob, Wt + 3 * MB, bo, d_out, nullptr, 4096, 1024, 1024);
}